// Round 5
// baseline (488.266 us; speedup 1.0000x reference)
//
#include <hip/hip_runtime.h>
#include <math.h>

#define N 8192
#define IN_F 256
#define OUT_F 128
#define ALPHA 0.2f
#define JS 8                 // j-range split
#define NSTEP 32             // 32-j steps per wave: (N/JS)/32
#define MW (N / 32)          // mask words per row = 256

typedef _Float16 f16;
typedef __attribute__((ext_vector_type(4))) float f32x4;
typedef __attribute__((ext_vector_type(8))) _Float16 f16x8;
typedef __attribute__((ext_vector_type(4))) _Float16 f16x4;

// ---------------- Kernel 0: WT[f][k] = (f16) W[k][f] ----------------
__global__ __launch_bounds__(256) void k_prep(const float* __restrict__ W,
                                              f16* __restrict__ WT) {
    int idx = blockIdx.x * 256 + threadIdx.x;
    int f = idx >> 8;
    int k = idx & 255;
    WT[idx] = (f16)W[k * OUT_F + f];
}

// ---------------- Kernel P: pack adj (int32 0/1) -> 1 bit, fully coalesced ----
// Lane-linear int4 reads stream at HBM peak; shfl assembles 32-bit words.
__global__ __launch_bounds__(256) void k_pack(const int* __restrict__ adj,
                                              unsigned* __restrict__ M) {
    const int t = threadIdx.x;
    const int l = t & 63;
    const size_t tot = (size_t)N * N / 4;              // 16M int4
    const size_t stride = (size_t)gridDim.x * 256;
    size_t idx = (size_t)blockIdx.x * 256 + t;
    const int4* ap = (const int4*)adj;
    for (; idx < tot; idx += stride) {
        int4 v = ap[idx];
        unsigned m = (v.x ? 1u : 0u) | (v.y ? 2u : 0u) | (v.z ? 4u : 0u) | (v.w ? 8u : 0u);
        m |= __shfl_down(m, 1) << 4;
        m |= __shfl_down(m, 2) << 8;
        m |= __shfl_down(m, 4) << 16;
        if ((l & 7) == 0) M[idx >> 3] = m;   // word w covers j = 32w .. 32w+31 (bit b = j offset b)
    }
}

// ---------------- Kernel 1: Wh = h@W via MFMA; emit tiled WhT(f16), src, dst ----
// WhT layout: [64 tiles][128 f][128 j_local]
#define HS 280
__global__ __launch_bounds__(256) void k_wh(const float* __restrict__ h,
                                            const f16* __restrict__ WT,
                                            const float* __restrict__ a,
                                            f16* __restrict__ WhT,
                                            float* __restrict__ src,
                                            float* __restrict__ dst) {
    __shared__ __align__(16) f16 hA[32][HS];
    __shared__ __align__(16) f16 outT[128][40];
    __shared__ float sred[4][32], dred[4][32];

    const int t = threadIdx.x;
    const int i0 = blockIdx.x * 32;
    const int wv = t >> 6, l = t & 63, ln = l & 15, lq = l >> 4;

    {
        const float4* hg = (const float4*)(h + (size_t)i0 * IN_F);
#pragma unroll
        for (int it = 0; it < 8; ++it) {
            int idx = t + it * 256;
            int r = idx >> 6;
            int c4 = (idx & 63) * 4;
            float4 v = hg[idx];
            f16x4 p = { (f16)v.x, (f16)v.y, (f16)v.z, (f16)v.w };
            *(f16x4*)&hA[r][c4] = p;
        }
    }
    __syncthreads();

    f32x4 acc00 = {0.f,0.f,0.f,0.f}, acc01 = {0.f,0.f,0.f,0.f};
    f32x4 acc10 = {0.f,0.f,0.f,0.f}, acc11 = {0.f,0.f,0.f,0.f};
    const int f0 = 32 * wv;

#pragma unroll
    for (int ks = 0; ks < 8; ++ks) {
        const int k0 = 32 * ks + 8 * lq;
        f16x8 a0 = *(const f16x8*)&hA[ln][k0];
        f16x8 a1 = *(const f16x8*)&hA[16 + ln][k0];
        f16x8 b0 = *(const f16x8*)(WT + (size_t)(f0 + ln) * IN_F + k0);
        f16x8 b1 = *(const f16x8*)(WT + (size_t)(f0 + 16 + ln) * IN_F + k0);
        acc00 = __builtin_amdgcn_mfma_f32_16x16x32_f16(a0, b0, acc00, 0, 0, 0);
        acc01 = __builtin_amdgcn_mfma_f32_16x16x32_f16(a0, b1, acc01, 0, 0, 0);
        acc10 = __builtin_amdgcn_mfma_f32_16x16x32_f16(a1, b0, acc10, 0, 0, 0);
        acc11 = __builtin_amdgcn_mfma_f32_16x16x32_f16(a1, b1, acc11, 0, 0, 0);
    }

    const float a1c0 = a[f0 + ln],      a2c0 = a[128 + f0 + ln];
    const float a1c1 = a[f0 + 16 + ln], a2c1 = a[128 + f0 + 16 + ln];
    float sp[8], dp[8];
#pragma unroll
    for (int i = 0; i < 8; ++i) { sp[i] = 0.f; dp[i] = 0.f; }

#pragma unroll
    for (int hh = 0; hh < 2; ++hh) {
        f32x4 v0 = hh ? acc10 : acc00;
        f32x4 v1 = hh ? acc11 : acc01;
        f16x4 p0, p1;
#pragma unroll
        for (int rg = 0; rg < 4; ++rg) {
            sp[hh * 4 + rg] += v0[rg] * a1c0 + v1[rg] * a1c1;
            dp[hh * 4 + rg] += v0[rg] * a2c0 + v1[rg] * a2c1;
            p0[rg] = (f16)v0[rg];
            p1[rg] = (f16)v1[rg];
        }
        *(f16x4*)&outT[f0 + ln][16 * hh + 4 * lq] = p0;
        *(f16x4*)&outT[f0 + 16 + ln][16 * hh + 4 * lq] = p1;
    }
#pragma unroll
    for (int i = 0; i < 8; ++i) {
        float s = sp[i], d = dp[i];
        s += __shfl_down(s, 8, 16); d += __shfl_down(d, 8, 16);
        s += __shfl_down(s, 4, 16); d += __shfl_down(d, 4, 16);
        s += __shfl_down(s, 2, 16); d += __shfl_down(d, 2, 16);
        s += __shfl_down(s, 1, 16); d += __shfl_down(d, 1, 16);
        if (ln == 0) {
            int row = 16 * (i >> 2) + 4 * lq + (i & 3);
            sred[wv][row] = s;
            dred[wv][row] = d;
        }
    }
    __syncthreads();
    if (t < 32) {
        src[i0 + t] = sred[0][t] + sred[1][t] + sred[2][t] + sred[3][t];
        dst[i0 + t] = dred[0][t] + dred[1][t] + dred[2][t] + dred[3][t];
    }
    {
        const int col = t & 127, g = t >> 7;
        const int ct = i0 >> 7, jo = i0 & 127;
        f16x8 q0 = *(const f16x8*)&outT[col][16 * g];
        f16x8 q1 = *(const f16x8*)&outT[col][16 * g + 8];
        f16* dstp = WhT + (size_t)ct * (128 * 128) + (size_t)col * 128 + jo + 16 * g;
        *(f16x8*)(dstp) = q0;
        *(f16x8*)(dstp + 8) = q1;
    }
}

// ---------------- Kernel 2: barrier-free fused attention partials ----------------
// One wave owns 32 rows x 1024 j. Adjacency comes from the packed bitmask
// (L2-resident): 16 B per row-set per 4 steps. No HBM in the hot loop.
__global__ __launch_bounds__(256, 2) void k_attn(const unsigned* __restrict__ M,
                                                 const f16* __restrict__ WhT,
                                                 const float* __restrict__ src,
                                                 const float* __restrict__ dst,
                                                 float* __restrict__ p_part,
                                                 float* __restrict__ l_part) {
    const int t = threadIdx.x;
    const int wv = t >> 6, l = t & 63, ln = l & 15, lq = l >> 4;
    const int i0 = (blockIdx.x * 4 + wv) * 32;
    const int jq = blockIdx.y;
    const int jbase = jq * (N / JS);

    const float src0 = src[i0 + ln];
    const float src1 = src[i0 + 16 + ln];
    const float c0 = fabsf(src0) + 4.0f;
    const float c1 = fabsf(src1) + 4.0f;
    float lp0 = 0.f, lp1 = 0.f;

    f32x4 acc0[8], acc1[8];
#pragma unroll
    for (int ft = 0; ft < 8; ++ft) {
        acc0[ft] = (f32x4){0.f,0.f,0.f,0.f};
        acc1[ft] = (f32x4){0.f,0.f,0.f,0.f};
    }

    const unsigned* Mr0 = M + (size_t)(i0 + ln) * MW + jq * (NSTEP);
    const unsigned* Mr1 = Mr0 + (size_t)16 * MW;
    const float* drow = dst + jbase + 8 * lq;
    const f16* Bb = WhT + (size_t)(jq * 8) * (128 * 128) + (size_t)ln * 128 + 8 * lq;

    // dst depth-2 rolling prefetch
    float4 pd[2][2];
    auto dissue = [&](int s, int p) {
        const int off = 32 * (s & (NSTEP - 1));
        pd[p][0] = *(const float4*)(drow + off);
        pd[p][1] = *(const float4*)(drow + off + 4);
    };
    // B depth-1 double buffer
    f16x8 bfb[2][8];
    auto bissue = [&](int s) {
        const int ss = s & (NSTEP - 1);
        const f16* bp = Bb + (ss >> 2) * (128 * 128) + (ss & 3) * 32;
#pragma unroll
        for (int ft = 0; ft < 8; ++ft)
            bfb[s & 1][ft] = *(const f16x8*)(bp + ft * (16 * 128));
    };

    uint4 m0c = *(const uint4*)Mr0;
    uint4 m1c = *(const uint4*)Mr1;
    dissue(0, 0);
    dissue(1, 1);
    bissue(0);

    for (int g = 0; g < 8; ++g) {
        uint4 m0n, m1n;
        if (g < 7) {
            m0n = *(const uint4*)(Mr0 + 4 * (g + 1));
            m1n = *(const uint4*)(Mr1 + 4 * (g + 1));
        }
#pragma unroll
        for (int s4 = 0; s4 < 4; ++s4) {
            const int s = 4 * g + s4;
            const int p = s & 1;
            const float4 d0 = pd[p][0], d1 = pd[p][1];
            dissue(s + 2, p);
            bissue(s + 1);
            const unsigned b0 = (((const unsigned*)&m0c)[s4] >> (8 * lq)) & 0xffu;
            const unsigned b1 = (((const unsigned*)&m1c)[s4] >> (8 * lq)) & 0xffu;
            const float* df0 = (const float*)&d0;
            const float* df1 = (const float*)&d1;
            f16x8 af0, af1;
#pragma unroll
            for (int k = 0; k < 8; ++k) {
                const float dv = (k < 4) ? df0[k] : df1[k - 4];
                float e0 = src0 + dv;
                float w0 = (b0 >> k) & 1u ? __expf(fmaxf(e0, ALPHA * e0) - c0) : 0.f;
                lp0 += w0; af0[k] = (f16)w0;
                float e1 = src1 + dv;
                float w1 = (b1 >> k) & 1u ? __expf(fmaxf(e1, ALPHA * e1) - c1) : 0.f;
                lp1 += w1; af1[k] = (f16)w1;
            }
#pragma unroll
            for (int ft = 0; ft < 8; ++ft) {
                f16x8 bf = bfb[p][ft];
                acc0[ft] = __builtin_amdgcn_mfma_f32_16x16x32_f16(af0, bf, acc0[ft], 0, 0, 0);
                acc1[ft] = __builtin_amdgcn_mfma_f32_16x16x32_f16(af1, bf, acc1[ft], 0, 0, 0);
            }
        }
        if (g < 7) { m0c = m0n; m1c = m1n; }
    }

    // reduce lp over the 4 lq-lanes of each row
    lp0 += __shfl_down(lp0, 32); lp0 += __shfl_down(lp0, 16);
    lp1 += __shfl_down(lp1, 32); lp1 += __shfl_down(lp1, 16);
    if (l < 16) {
        l_part[(size_t)jq * N + i0 + l] = lp0;
        l_part[(size_t)jq * N + i0 + 16 + l] = lp1;
    }

    // store partial accumulators (C layout: col=ln, row=4*lq+rg)
    float* pb = p_part + (size_t)jq * N * OUT_F;
#pragma unroll
    for (int ft = 0; ft < 8; ++ft) {
#pragma unroll
        for (int rg = 0; rg < 4; ++rg) {
            pb[(size_t)(i0 + 4 * lq + rg) * OUT_F + 16 * ft + ln] = acc0[ft][rg];
            pb[(size_t)(i0 + 16 + 4 * lq + rg) * OUT_F + 16 * ft + ln] = acc1[ft][rg];
        }
    }
}

// ---------------- Kernel 3: combine j-eighth partials, normalize, ELU ----------------
__global__ __launch_bounds__(256) void k_comb(const float* __restrict__ p_part,
                                              const float* __restrict__ l_part,
                                              float* __restrict__ out) {
    const int idx4 = blockIdx.x * 256 + threadIdx.x;
    const int row = idx4 >> 5;
    const float4* pp = (const float4*)p_part;
    float4 p = pp[idx4];
    float lsum = l_part[row];
#pragma unroll
    for (int q = 1; q < JS; ++q) {
        float4 v = pp[(size_t)q * (N * OUT_F / 4) + idx4];
        p.x += v.x; p.y += v.y; p.z += v.z; p.w += v.w;
        lsum += l_part[(size_t)q * N + row];
    }
    float inv = 1.0f / lsum;
    float4 r;
    r.x = p.x * inv; r.x = r.x > 0.f ? r.x : expm1f(r.x);
    r.y = p.y * inv; r.y = r.y > 0.f ? r.y : expm1f(r.y);
    r.z = p.z * inv; r.z = r.z > 0.f ? r.z : expm1f(r.z);
    r.w = p.w * inv; r.w = r.w > 0.f ? r.w : expm1f(r.w);
    ((float4*)out)[idx4] = r;
}

extern "C" void kernel_launch(void* const* d_in, const int* in_sizes, int n_in,
                              void* d_out, int out_size, void* d_ws, size_t ws_size,
                              hipStream_t stream) {
    const float* h   = (const float*)d_in[0];
    const int*   adj = (const int*)d_in[1];
    const float* W   = (const float*)d_in[2];
    const float* a   = (const float*)d_in[3];
    float* out = (float*)d_out;

    char* ws = (char*)d_ws;
    f16*      WT     = (f16*)ws;        ws += 64 * 1024;
    f16*      WhT    = (f16*)ws;        ws += 2 * 1024 * 1024;
    float*    src    = (float*)ws;      ws += N * sizeof(float);
    float*    dst    = (float*)ws;      ws += N * sizeof(float);
    float*    l_part = (float*)ws;      ws += (size_t)JS * N * sizeof(float);
    unsigned* M      = (unsigned*)ws;   ws += (size_t)N * MW * sizeof(unsigned);  // 8 MB
    float*    p_part = (float*)ws;      // JS * N * OUT_F * 4 = 32 MB

    k_pack<<<2048, 256, 0, stream>>>(adj, M);
    k_prep<<<128, 256, 0, stream>>>(W, WT);
    k_wh<<<N / 32, 256, 0, stream>>>(h, WT, a, WhT, src, dst);
    dim3 agrid(N / 128, JS);
    k_attn<<<agrid, 256, 0, stream>>>(M, WhT, src, dst, p_part, l_part);
    k_comb<<<N * OUT_F / 4 / 256, 256, 0, stream>>>(p_part, l_part, out);
}

// Round 6
// 418.966 us; speedup vs baseline: 1.1654x; 1.1654x over previous
//
#include <hip/hip_runtime.h>
#include <math.h>

#define N 8192
#define IN_F 256
#define OUT_F 128
#define ALPHA 0.2f
#define JS 8                 // j-range split
#define NSTEP 32             // 32-j steps per wave: (N/JS)/32
#define MW (N / 32)          // mask words per row = 256

typedef _Float16 f16;
typedef __attribute__((ext_vector_type(4))) float f32x4;
typedef __attribute__((ext_vector_type(8))) _Float16 f16x8;
typedef __attribute__((ext_vector_type(4))) _Float16 f16x4;

// ---------------- Kernel 0: WT[f][k] = (f16) W[k][f] ----------------
__global__ __launch_bounds__(256) void k_prep(const float* __restrict__ W,
                                              f16* __restrict__ WT) {
    int idx = blockIdx.x * 256 + threadIdx.x;
    int f = idx >> 8;
    int k = idx & 255;
    WT[idx] = (f16)W[k * OUT_F + f];
}

// ---------------- Kernel P: pack adj (int32 0/1) -> 1 bit, fully coalesced ----
__global__ __launch_bounds__(256) void k_pack(const int* __restrict__ adj,
                                              unsigned* __restrict__ M) {
    const int t = threadIdx.x;
    const int l = t & 63;
    const size_t tot = (size_t)N * N / 4;              // 16M int4
    const size_t stride = (size_t)gridDim.x * 256;
    size_t idx = (size_t)blockIdx.x * 256 + t;
    const int4* ap = (const int4*)adj;
    for (; idx < tot; idx += stride) {
        int4 v = ap[idx];
        unsigned m = (v.x ? 1u : 0u) | (v.y ? 2u : 0u) | (v.z ? 4u : 0u) | (v.w ? 8u : 0u);
        m |= __shfl_down(m, 1) << 4;
        m |= __shfl_down(m, 2) << 8;
        m |= __shfl_down(m, 4) << 16;
        if ((l & 7) == 0) M[idx >> 3] = m;   // word w covers j = 32w..32w+31
    }
}

// ---------------- Kernel 1: Wh = h@W via MFMA; emit Bpack(f16), src, dst ----
// Bpack: MFMA B-fragment order. Slot (gs, ft, lane): value =
//   Wh[node j = 32*gs + 8*(lane>>4) + k][f = 16*ft + (lane&15)], k=0..7.
// Each k_attn B-load is then one lane-linear contiguous 1 KB read.
#define HS 280
__global__ __launch_bounds__(256) void k_wh(const float* __restrict__ h,
                                            const f16* __restrict__ WT,
                                            const float* __restrict__ a,
                                            f16* __restrict__ Bpack,
                                            float* __restrict__ src,
                                            float* __restrict__ dst) {
    __shared__ __align__(16) f16 hA[32][HS];
    __shared__ __align__(16) f16 outT[128][40];
    __shared__ float sred[4][32], dred[4][32];

    const int t = threadIdx.x;
    const int i0 = blockIdx.x * 32;
    const int wv = t >> 6, l = t & 63, ln = l & 15, lq = l >> 4;

    {
        const float4* hg = (const float4*)(h + (size_t)i0 * IN_F);
#pragma unroll
        for (int it = 0; it < 8; ++it) {
            int idx = t + it * 256;
            int r = idx >> 6;
            int c4 = (idx & 63) * 4;
            float4 v = hg[idx];
            f16x4 p = { (f16)v.x, (f16)v.y, (f16)v.z, (f16)v.w };
            *(f16x4*)&hA[r][c4] = p;
        }
    }
    __syncthreads();

    f32x4 acc00 = {0.f,0.f,0.f,0.f}, acc01 = {0.f,0.f,0.f,0.f};
    f32x4 acc10 = {0.f,0.f,0.f,0.f}, acc11 = {0.f,0.f,0.f,0.f};
    const int f0 = 32 * wv;

#pragma unroll
    for (int ks = 0; ks < 8; ++ks) {
        const int k0 = 32 * ks + 8 * lq;
        f16x8 a0 = *(const f16x8*)&hA[ln][k0];
        f16x8 a1 = *(const f16x8*)&hA[16 + ln][k0];
        f16x8 b0 = *(const f16x8*)(WT + (size_t)(f0 + ln) * IN_F + k0);
        f16x8 b1 = *(const f16x8*)(WT + (size_t)(f0 + 16 + ln) * IN_F + k0);
        acc00 = __builtin_amdgcn_mfma_f32_16x16x32_f16(a0, b0, acc00, 0, 0, 0);
        acc01 = __builtin_amdgcn_mfma_f32_16x16x32_f16(a0, b1, acc01, 0, 0, 0);
        acc10 = __builtin_amdgcn_mfma_f32_16x16x32_f16(a1, b0, acc10, 0, 0, 0);
        acc11 = __builtin_amdgcn_mfma_f32_16x16x32_f16(a1, b1, acc11, 0, 0, 0);
    }

    const float a1c0 = a[f0 + ln],      a2c0 = a[128 + f0 + ln];
    const float a1c1 = a[f0 + 16 + ln], a2c1 = a[128 + f0 + 16 + ln];
    float sp[8], dp[8];
#pragma unroll
    for (int i = 0; i < 8; ++i) { sp[i] = 0.f; dp[i] = 0.f; }

#pragma unroll
    for (int hh = 0; hh < 2; ++hh) {
        f32x4 v0 = hh ? acc10 : acc00;
        f32x4 v1 = hh ? acc11 : acc01;
        f16x4 p0, p1;
#pragma unroll
        for (int rg = 0; rg < 4; ++rg) {
            sp[hh * 4 + rg] += v0[rg] * a1c0 + v1[rg] * a1c1;
            dp[hh * 4 + rg] += v0[rg] * a2c0 + v1[rg] * a2c1;
            p0[rg] = (f16)v0[rg];
            p1[rg] = (f16)v1[rg];
        }
        *(f16x4*)&outT[f0 + ln][16 * hh + 4 * lq] = p0;
        *(f16x4*)&outT[f0 + 16 + ln][16 * hh + 4 * lq] = p1;
    }
#pragma unroll
    for (int i = 0; i < 8; ++i) {
        float s = sp[i], d = dp[i];
        s += __shfl_down(s, 8, 16); d += __shfl_down(d, 8, 16);
        s += __shfl_down(s, 4, 16); d += __shfl_down(d, 4, 16);
        s += __shfl_down(s, 2, 16); d += __shfl_down(d, 2, 16);
        s += __shfl_down(s, 1, 16); d += __shfl_down(d, 1, 16);
        if (ln == 0) {
            int row = 16 * (i >> 2) + 4 * lq + (i & 3);
            sred[wv][row] = s;
            dred[wv][row] = d;
        }
    }
    __syncthreads();
    if (t < 32) {
        src[i0 + t] = sred[0][t] + sred[1][t] + sred[2][t] + sred[3][t];
        dst[i0 + t] = dred[0][t] + dred[1][t] + dred[2][t] + dred[3][t];
    }
    // write Bpack: this block is global j-step gs = i0/32
    {
        const size_t gs = (size_t)(i0 >> 5);
        const int ft0 = t >> 6;                 // 0..3, lane = l
#pragma unroll
        for (int hh = 0; hh < 2; ++hh) {
            const int ft = ft0 + 4 * hh;
            f16x8 v = *(const f16x8*)&outT[16 * ft + ln][8 * lq];
            *(f16x8*)(Bpack + (gs * 8 + ft) * 512 + l * 8) = v;
        }
    }
}

// ---------------- Kernel 2: barrier-free fused attention partials ----------------
// One wave owns 32 rows x 1024 j. Spill-free: launch_bounds(256,1) lifts the
// VGPR cap; B-fragments are transient per-step contiguous 1KB loads (Bpack).
__global__ __launch_bounds__(256, 1) void k_attn(const unsigned* __restrict__ M,
                                                 const f16* __restrict__ Bpack,
                                                 const float* __restrict__ src,
                                                 const float* __restrict__ dst,
                                                 float* __restrict__ p_part,
                                                 float* __restrict__ l_part) {
    const int t = threadIdx.x;
    const int wv = t >> 6, l = t & 63, ln = l & 15, lq = l >> 4;
    const int i0 = (blockIdx.x * 4 + wv) * 32;
    const int jq = blockIdx.y;

    const float src0 = src[i0 + ln];
    const float src1 = src[i0 + 16 + ln];
    const float c0 = fabsf(src0) + 4.0f;
    const float c1 = fabsf(src1) + 4.0f;
    float lp0 = 0.f, lp1 = 0.f;

    f32x4 acc0[8], acc1[8];
#pragma unroll
    for (int ft = 0; ft < 8; ++ft) {
        acc0[ft] = (f32x4){0.f,0.f,0.f,0.f};
        acc1[ft] = (f32x4){0.f,0.f,0.f,0.f};
    }

    const unsigned* Mr0 = M + (size_t)(i0 + ln) * MW + jq * NSTEP;
    const unsigned* Mr1 = Mr0 + (size_t)16 * MW;
    const float* drow = dst + jq * (N / JS) + 8 * lq;
    const f16* Bb = Bpack + (size_t)(jq * NSTEP) * 8 * 512 + l * 8;

    uint4 m0c = *(const uint4*)Mr0;
    uint4 m1c = *(const uint4*)Mr1;
    float4 cd0 = *(const float4*)(drow);
    float4 cd1 = *(const float4*)(drow + 4);

    for (int g = 0; g < 8; ++g) {
        uint4 m0n, m1n;
        if (g < 7) {
            m0n = *(const uint4*)(Mr0 + 4 * (g + 1));
            m1n = *(const uint4*)(Mr1 + 4 * (g + 1));
        }
#pragma unroll
        for (int s4 = 0; s4 < 4; ++s4) {
            const int s = 4 * g + s4;
            // B fragments for this step: 8 contiguous 1KB lane-linear loads
            const f16* bp = Bb + (size_t)s * (8 * 512);
            f16x8 bf[8];
#pragma unroll
            for (int ft = 0; ft < 8; ++ft)
                bf[ft] = *(const f16x8*)(bp + ft * 512);
            // dst: consume current, prefetch next step
            const float4 d0 = cd0, d1 = cd1;
            {
                const int off = 32 * ((s + 1) & (NSTEP - 1));
                cd0 = *(const float4*)(drow + off);
                cd1 = *(const float4*)(drow + off + 4);
            }
            const unsigned b0 = (((const unsigned*)&m0c)[s4] >> (8 * lq)) & 0xffu;
            const unsigned b1 = (((const unsigned*)&m1c)[s4] >> (8 * lq)) & 0xffu;
            const float* df0 = (const float*)&d0;
            const float* df1 = (const float*)&d1;
            f16x8 af0, af1;
#pragma unroll
            for (int k = 0; k < 8; ++k) {
                const float dv = (k < 4) ? df0[k] : df1[k - 4];
                float e0 = src0 + dv;
                float w0 = (b0 >> k) & 1u ? __expf(fmaxf(e0, ALPHA * e0) - c0) : 0.f;
                lp0 += w0; af0[k] = (f16)w0;
                float e1 = src1 + dv;
                float w1 = (b1 >> k) & 1u ? __expf(fmaxf(e1, ALPHA * e1) - c1) : 0.f;
                lp1 += w1; af1[k] = (f16)w1;
            }
#pragma unroll
            for (int ft = 0; ft < 8; ++ft) {
                acc0[ft] = __builtin_amdgcn_mfma_f32_16x16x32_f16(af0, bf[ft], acc0[ft], 0, 0, 0);
                acc1[ft] = __builtin_amdgcn_mfma_f32_16x16x32_f16(af1, bf[ft], acc1[ft], 0, 0, 0);
            }
        }
        if (g < 7) { m0c = m0n; m1c = m1n; }
    }

    // reduce lp over the 4 lq-lanes of each row
    lp0 += __shfl_down(lp0, 32); lp0 += __shfl_down(lp0, 16);
    lp1 += __shfl_down(lp1, 32); lp1 += __shfl_down(lp1, 16);
    if (l < 16) {
        l_part[(size_t)jq * N + i0 + l] = lp0;
        l_part[(size_t)jq * N + i0 + 16 + l] = lp1;
    }

    // store partial accumulators (C layout: col=ln, row=4*lq+rg)
    float* pb = p_part + (size_t)jq * N * OUT_F;
#pragma unroll
    for (int ft = 0; ft < 8; ++ft) {
#pragma unroll
        for (int rg = 0; rg < 4; ++rg) {
            pb[(size_t)(i0 + 4 * lq + rg) * OUT_F + 16 * ft + ln] = acc0[ft][rg];
            pb[(size_t)(i0 + 16 + 4 * lq + rg) * OUT_F + 16 * ft + ln] = acc1[ft][rg];
        }
    }
}

// ---------------- Kernel 3: combine j-eighth partials, normalize, ELU ----------------
__global__ __launch_bounds__(256) void k_comb(const float* __restrict__ p_part,
                                              const float* __restrict__ l_part,
                                              float* __restrict__ out) {
    const int idx4 = blockIdx.x * 256 + threadIdx.x;
    const int row = idx4 >> 5;
    const float4* pp = (const float4*)p_part;
    float4 p = pp[idx4];
    float lsum = l_part[row];
#pragma unroll
    for (int q = 1; q < JS; ++q) {
        float4 v = pp[(size_t)q * (N * OUT_F / 4) + idx4];
        p.x += v.x; p.y += v.y; p.z += v.z; p.w += v.w;
        lsum += l_part[(size_t)q * N + row];
    }
    float inv = 1.0f / lsum;
    float4 r;
    r.x = p.x * inv; r.x = r.x > 0.f ? r.x : expm1f(r.x);
    r.y = p.y * inv; r.y = r.y > 0.f ? r.y : expm1f(r.y);
    r.z = p.z * inv; r.z = r.z > 0.f ? r.z : expm1f(r.z);
    r.w = p.w * inv; r.w = r.w > 0.f ? r.w : expm1f(r.w);
    ((float4*)out)[idx4] = r;
}

extern "C" void kernel_launch(void* const* d_in, const int* in_sizes, int n_in,
                              void* d_out, int out_size, void* d_ws, size_t ws_size,
                              hipStream_t stream) {
    const float* h   = (const float*)d_in[0];
    const int*   adj = (const int*)d_in[1];
    const float* W   = (const float*)d_in[2];
    const float* a   = (const float*)d_in[3];
    float* out = (float*)d_out;

    char* ws = (char*)d_ws;
    f16*      WT     = (f16*)ws;        ws += 64 * 1024;
    f16*      Bpack  = (f16*)ws;        ws += 2 * 1024 * 1024;
    float*    src    = (float*)ws;      ws += N * sizeof(float);
    float*    dst    = (float*)ws;      ws += N * sizeof(float);
    float*    l_part = (float*)ws;      ws += (size_t)JS * N * sizeof(float);
    unsigned* M      = (unsigned*)ws;   ws += (size_t)N * MW * sizeof(unsigned);  // 8 MB
    float*    p_part = (float*)ws;      // JS * N * OUT_F * 4 = 32 MB

    k_pack<<<2048, 256, 0, stream>>>(adj, M);
    k_prep<<<128, 256, 0, stream>>>(W, WT);
    k_wh<<<N / 32, 256, 0, stream>>>(h, WT, a, Bpack, src, dst);
    dim3 agrid(N / 128, JS);
    k_attn<<<agrid, 256, 0, stream>>>(M, Bpack, src, dst, p_part, l_part);
    k_comb<<<N * OUT_F / 4 / 256, 256, 0, stream>>>(p_part, l_part, out);
}